// Round 3
// baseline (189.352 us; speedup 1.0000x reference)
//
#include <hip/hip_runtime.h>

#define HW   50176      // 224*224
#define NBLK 196        // HW / 256  (blocks per batch; 128 thr x 2 px = 256 px/blk)
#define NPAR 4576       // KAN_PARAMS_NUM

// ---------------------------------------------------------------------------
// Stage 1: w[b][n] = sum_k features[b][k] * fc_w[n][k] + fc_b[n]
// 1144 blocks, one n per wave. All 4 float4 row-loads issued independently
// up front (MLP=4/lane), features staged once per block in LDS.
// ---------------------------------------------------------------------------
__global__ __launch_bounds__(256) void gemm_w(const float* __restrict__ feats,
                                              const float* __restrict__ fcw,
                                              const float* __restrict__ fcb,
                                              float* __restrict__ wout) {
    __shared__ float fl[8000];
    int tid = threadIdx.x;
    const float4* f4 = (const float4*)feats;
    float4* fl4 = (float4*)fl;
#pragma unroll
    for (int r = 0; r < 8; r++) {
        int idx = r * 256 + tid;
        if (idx < 2000) fl4[idx] = f4[idx];
    }
    __syncthreads();

    int wave = tid >> 6, lane = tid & 63;
    int n = blockIdx.x * 4 + wave;           // 0..4575
    const float4* wrow = (const float4*)(fcw + (size_t)n * 1000);

    // 250 float4 per row; 4 independent loads per lane (lane<58 guard on last)
    float4 z = {0.f, 0.f, 0.f, 0.f};
    float4 wv0 = wrow[lane];
    float4 wv1 = wrow[lane + 64];
    float4 wv2 = wrow[lane + 128];
    float4 wv3 = (lane < 58) ? wrow[lane + 192] : z;

    float acc[8];
#pragma unroll
    for (int b = 0; b < 8; b++) acc[b] = 0.f;

#pragma unroll
    for (int b = 0; b < 8; b++) {
        const float4* fb = fl4 + b * 250;
        float4 f0 = fb[lane];
        float4 f1 = fb[lane + 64];
        float4 f2 = fb[lane + 128];
        float4 f3 = (lane < 58) ? fb[lane + 192] : z;
        float s;
        s  = wv0.x * f0.x + wv0.y * f0.y + wv0.z * f0.z + wv0.w * f0.w;
        s += wv1.x * f1.x + wv1.y * f1.y + wv1.z * f1.z + wv1.w * f1.w;
        s += wv2.x * f2.x + wv2.y * f2.y + wv2.z * f2.z + wv2.w * f2.w;
        s += wv3.x * f3.x + wv3.y * f3.y + wv3.z * f3.z + wv3.w * f3.w;
        acc[b] = s;
    }

#pragma unroll
    for (int b = 0; b < 8; b++) {
        float v = acc[b];
#pragma unroll
        for (int off = 32; off > 0; off >>= 1) v += __shfl_down(v, off, 64);
        if (lane == 0) wout[b * NPAR + n] = v + fcb[n];
    }
}

// ---------------------------------------------------------------------------
// Stage 1.5: in-place coef *= uw. Coef slots written once; uw only read.
// ---------------------------------------------------------------------------
__global__ __launch_bounds__(256) void premult(float* __restrict__ w) {
    int j = blockIdx.x * 256 + threadIdx.x;
    if (j >= 8 * 3872) return;
    int b = j / 3872, c = j - b * 3872;
    int base, uwbase, cc;
    if (c < 528)       { cc = c;        base = 0;    uwbase = 528;  }
    else if (c < 3344) { cc = c - 528;  base = 624;  uwbase = 3440; }
    else               { cc = c - 3344; base = 3952; uwbase = 4480; }
    int oi = cc / 11;              // i*DO + o
    float* wb = w + b * NPAR;
    wb[base + cc] *= wb[uwbase + oi];
}

// ---------------------------------------------------------------------------
// Cardinal cubic basis scatter for one value; bb[K0..10] filled.
// ---------------------------------------------------------------------------
template <int K0>
__device__ __forceinline__ void basis_scatter(float yi, float* bb) {
    float t  = (yi + 1.75f) * 4.0f;
    float ft = floorf(t);
    ft = fminf(fmaxf(ft, 0.f), 13.f);
    float u  = t - ft;
    float u2 = u * u, u3 = u2 * u;
    float omu = 1.f - u;
    float b0 = (1.f / 6.f) * omu * omu * omu;
    float b3 = (1.f / 6.f) * u3;
    float b1 = 0.5f * u3 - u2 + (2.f / 3.f);
    float b2 = 1.f - b0 - b1 - b3;
    int jt = (int)ft;
    if (!(t >= 0.f && t < 14.f)) jt = 99;   // out-of-domain -> all-zero basis
#pragma unroll
    for (int k = K0; k < 11; k++) {
        float v = (jt == k + 3) ? b0 : 0.f;
        v = (jt == k + 2) ? b1 : v;
        v = (jt == k + 1) ? b2 : v;
        v = (jt == k)     ? b3 : v;
        bb[k] = v;
    }
}

// Two pixels sharing one SGPR coefficient stream.
// cw: premultiplied coef (DO*11), rw: DO floats. acc statically indexed.
template <int DO, int K0>
__device__ __forceinline__ void kan_step2(float y0, float y1,
                                          const float* __restrict__ cw,
                                          const float* __restrict__ rw,
                                          float* acc0, float* acc1) {
    float bb0[11], bb1[11];
    basis_scatter<K0>(y0, bb0);
    basis_scatter<K0>(y1, bb1);
    float sil0 = y0 / (1.f + __expf(-y0));
    float sil1 = y1 / (1.f + __expf(-y1));
#pragma unroll
    for (int o = 0; o < DO; o++) {
#pragma unroll
        for (int k = K0; k < 11; k++) {
            float c = cw[o * 11 + k];
            acc0[o] = fmaf(bb0[k], c, acc0[o]);
            acc1[o] = fmaf(bb1[k], c, acc1[o]);
        }
        float r = rw[o];
        acc0[o] = fmaf(sil0, r, acc0[o]);
        acc1[o] = fmaf(sil1, r, acc1[o]);
    }
}

// ---------------------------------------------------------------------------
// Stage 2: per-pixel KAN (3 -> 16 -> 16 -> 3), 2 pixels per thread.
// 128-thread blocks, each covering 256 consecutive pixels of one batch
// (param pointer block-uniform -> s_load coefficients, shared by both pixels).
// ---------------------------------------------------------------------------
__global__ __launch_bounds__(128) void kan_eval(const float* __restrict__ x,
                                                const float* __restrict__ wv,
                                                float* __restrict__ out) {
    __shared__ float h[16 * 256];
    int tid = threadIdx.x;                   // 0..127
    int b = blockIdx.x / NBLK;
    int hw = (blockIdx.x - b * NBLK) * 256 + tid;   // pixel 0; pixel 1 = +128

    const float* wp = wv + b * NPAR;                 // block-uniform
    const float* xb = x + (size_t)b * 3 * HW + hw;

    // ---- layer 1: DI=3, DO=16. coef@0 (premult), rw@576. t in [7,11) -> k>=4
    float A0[16], A1[16];
#pragma unroll
    for (int o = 0; o < 16; o++) { A0[o] = 0.f; A1[o] = 0.f; }
    kan_step2<16, 4>(xb[0],      xb[128],          wp + 0,   wp + 576,      A0, A1);
    kan_step2<16, 4>(xb[HW],     xb[HW + 128],     wp + 176, wp + 576 + 16, A0, A1);
    kan_step2<16, 4>(xb[2 * HW], xb[2 * HW + 128], wp + 352, wp + 576 + 32, A0, A1);
#pragma unroll
    for (int o = 0; o < 16; o++) {
        h[o * 256 + tid] = A0[o];
        h[o * 256 + 128 + tid] = A1[o];
    }

    // ---- layer 2: DI=16, DO=16. coef@624 (premult), rw@3696
    float B0[16], B1[16];
#pragma unroll
    for (int o = 0; o < 16; o++) { B0[o] = 0.f; B1[o] = 0.f; }
#pragma unroll 1
    for (int i = 0; i < 16; i++) {
        float y0 = h[i * 256 + tid];
        float y1 = h[i * 256 + 128 + tid];
        kan_step2<16, 0>(y0, y1, wp + 624 + i * 176, wp + 3696 + i * 16, B0, B1);
    }
    __syncthreads();   // layer-1 slots about to be overwritten
#pragma unroll
    for (int o = 0; o < 16; o++) {
        h[o * 256 + tid] = B0[o];
        h[o * 256 + 128 + tid] = B1[o];
    }

    // ---- layer 3: DI=16, DO=3. coef@3952 (premult), rw@4528
    float C0[3] = {0.f, 0.f, 0.f};
    float C1[3] = {0.f, 0.f, 0.f};
#pragma unroll 1
    for (int i = 0; i < 16; i++) {
        float y0 = h[i * 256 + tid];
        float y1 = h[i * 256 + 128 + tid];
        kan_step2<3, 0>(y0, y1, wp + 3952 + i * 33, wp + 4528 + i * 3, C0, C1);
    }

    float* ob = out + (size_t)b * 3 * HW + hw;
#pragma unroll
    for (int c = 0; c < 3; c++) {
        ob[c * HW]       = C0[c];
        ob[c * HW + 128] = C1[c];
    }
}

// ---------------------------------------------------------------------------
extern "C" void kernel_launch(void* const* d_in, const int* in_sizes, int n_in,
                              void* d_out, int out_size, void* d_ws, size_t ws_size,
                              hipStream_t stream) {
    const float* x     = (const float*)d_in[0];   // (8,3,224,224)
    const float* feats = (const float*)d_in[1];   // (8,1000)
    const float* fcw   = (const float*)d_in[2];   // (4576,1000)
    const float* fcb   = (const float*)d_in[3];   // (4576,)
    float* outp = (float*)d_out;                  // (8,3,224,224)
    float* wbuf = (float*)d_ws;                   // 8*4576 floats = 146 KB

    hipLaunchKernelGGL(gemm_w, dim3(NPAR / 4), dim3(256), 0, stream,
                       feats, fcw, fcb, wbuf);
    hipLaunchKernelGGL(premult, dim3((8 * 3872 + 255) / 256), dim3(256), 0, stream,
                       wbuf);
    hipLaunchKernelGGL(kan_eval, dim3(8 * NBLK), dim3(128), 0, stream,
                       x, wbuf, outp);
}

// Round 6
// 129.609 us; speedup vs baseline: 1.4610x; 1.4610x over previous
//
#include <hip/hip_runtime.h>

#define HW   50176      // 224*224
#define NPAR 4576       // KAN_PARAMS_NUM

typedef _Float16 half8 __attribute__((ext_vector_type(8)));
typedef __attribute__((ext_vector_type(4))) float f32x4;
typedef __attribute__((ext_vector_type(4))) int int4v;

__device__ __forceinline__ unsigned short f2h(float f) {
    union { _Float16 h; unsigned short u; } c; c.h = (_Float16)f; return c.u;
}
__device__ __forceinline__ float h2f(unsigned short u) {
    union { _Float16 h; unsigned short u; } c; c.u = u; return (float)c.h;
}

// ---------------------------------------------------------------------------
// Stage 1: w[m][n] = features[m][:] . fc_w[n][:] + fc_b[n]  via fp16 MFMA.
// M=8 (pad 16), N=4576 (286 tiles of 16), K=1000 (32 ksteps of 32).
// features split hi+lo fp16 (2 MFMAs/step) so only fcw's single fp16
// rounding survives -> w abs err ~1e-3 (negligible downstream).
// ---------------------------------------------------------------------------
__global__ __launch_bounds__(64) void gemm_w(const float* __restrict__ feats,
                                             const float* __restrict__ fcw,
                                             const float* __restrict__ fcb,
                                             float* __restrict__ wout) {
    int lane = threadIdx.x, nn = lane & 15, quad = lane >> 4;
    int n = blockIdx.x * 16 + nn;
    const float* brow = fcw + (size_t)n * 1000;
    const float* arow = feats + nn * 1000;          // deref'd only if nn<8

    f32x4 acc = {0.f, 0.f, 0.f, 0.f};
#pragma unroll 2
    for (int s = 0; s < 32; s++) {
        int kb = s * 32 + quad * 8;
        float4 a0 = {0,0,0,0}, a1 = {0,0,0,0}, b0 = {0,0,0,0}, b1 = {0,0,0,0};
        if (kb < 1000) {                            // 1000 % 8 == 0
            b0 = *(const float4*)(brow + kb);
            b1 = *(const float4*)(brow + kb + 4);
            if (nn < 8) {
                a0 = *(const float4*)(arow + kb);
                a1 = *(const float4*)(arow + kb + 4);
            }
        }
        float af[8] = {a0.x, a0.y, a0.z, a0.w, a1.x, a1.y, a1.z, a1.w};
        float bf[8] = {b0.x, b0.y, b0.z, b0.w, b1.x, b1.y, b1.z, b1.w};
        half8 ah, al, bh;
#pragma unroll
        for (int j = 0; j < 8; j++) {
            ah[j] = (_Float16)af[j];
            al[j] = (_Float16)(af[j] - (float)ah[j]);
            bh[j] = (_Float16)bf[j];
        }
        acc = __builtin_amdgcn_mfma_f32_16x16x32_f16(ah, bh, acc, 0, 0, 0);
        acc = __builtin_amdgcn_mfma_f32_16x16x32_f16(al, bh, acc, 0, 0, 0);
    }
    if (quad < 2) {                                  // rows m = quad*4+r in [0,8)
        float bias = fcb[n];
#pragma unroll
        for (int r = 0; r < 4; r++)
            wout[(size_t)(quad * 4 + r) * NPAR + n] = acc[r] + bias;
    }
}

// ---------------------------------------------------------------------------
// Stage 1.5: build frag-ready fp16 B tensor in ws.
// bt[b*4608 + ks*256 + ln*4 + dq], ks: 0-1 L1, 2-9 L2, 10-17 L3.
// Lane ln (q=ln>>4, n=ln&15) dword dq holds halves rk=(q&1)*8+dq*2+{0,1} of
// channel i=2s+(q>>1): rk<11 -> coef*uw, 11/12 -> rw, 13 -> rw_lo.
// ---------------------------------------------------------------------------
__global__ __launch_bounds__(256) void pack_b(const float* __restrict__ w,
                                              unsigned int* __restrict__ bt) {
    int idx = blockIdx.x * 256 + threadIdx.x;       // < 36864
    if (idx >= 8 * 4608) return;
    int b = idx / 4608, r = idx - b * 4608;
    int ks = r >> 8, ln = (r >> 2) & 63, dq = r & 3;
    int q = ln >> 4, n = ln & 15;
    int lay, s;
    if (ks < 2)       { lay = 0; s = ks; }
    else if (ks < 10) { lay = 1; s = ks - 2; }
    else              { lay = 2; s = ks - 10; }
    int i = 2 * s + (q >> 1);
    const float* wb = w + b * NPAR;
    int cb, ub, rb2, nd, ni;
    if (lay == 0)      { cb = 0;    ub = 528;  rb2 = 576;  nd = 16; ni = 3;  }
    else if (lay == 1) { cb = 624;  ub = 3440; rb2 = 3696; nd = 16; ni = 16; }
    else               { cb = 3952; ub = 4480; rb2 = 4528; nd = 3;  ni = 16; }
    unsigned int pk = 0;
    if (i < ni && n < nd) {
        float uwv = wb[ub + i * nd + n];
        float rwv = wb[rb2 + i * nd + n];
        unsigned short rh = f2h(rwv);
        float rl = rwv - h2f(rh);
#pragma unroll
        for (int h = 0; h < 2; h++) {
            int rk = (q & 1) * 8 + dq * 2 + h;
            float v = 0.f;
            if (rk < 11)       v = wb[cb + (i * nd + n) * 11 + rk] * uwv;
            else if (rk < 13)  v = rwv;
            else if (rk == 13) v = rl;
            pk |= ((unsigned int)f2h(v)) << (16 * h);
        }
    }
    bt[idx] = pk;
}

// ---------------------------------------------------------------------------
// Scatter one channel-row (16 fp16 slots) into its two 4-dword LDS groups.
// g0: slots 0-7, g1: slots 8-15 (both 16B aligned).
//   slots 0-10: cardinal cubic taps at jt-3..jt (others zero)
//   slot 11 = sil_hi, 12 = sil_lo, 13 = sil_hi, 14-15 = 0
// ---------------------------------------------------------------------------
__device__ __forceinline__ void scatter_row(int* g0, int* g1, float y) {
    float t  = (y + 1.75f) * 4.0f;
    float ft = floorf(t);
    ft = fminf(fmaxf(ft, -8.0f), 24.0f);
    int jt  = (int)ft;
    float u = t - ft;
    float u2 = u * u, u3 = u2 * u, om = 1.0f - u;
    float b0 = (1.0f / 6.0f) * om * om * om;
    float b3 = (1.0f / 6.0f) * u3;
    float b1 = 0.5f * u3 - u2 + (2.0f / 3.0f);
    float b2 = 1.0f - b0 - b1 - b3;
    float sil = y / (1.0f + __expf(-y));
    unsigned short sh = f2h(sil);
    float sl = sil - h2f(sh);
    float t10 = 0.f;
    t10 = (jt == 13) ? b0 : t10;
    t10 = (jt == 12) ? b1 : t10;
    t10 = (jt == 11) ? b2 : t10;
    t10 = (jt == 10) ? b3 : t10;
    int4v z = {0, 0, 0, 0};
    int4v w1;
    w1[0] = 0;
    w1[1] = (int)((unsigned int)f2h(t10) | ((unsigned int)sh << 16));  // 10,11
    w1[2] = (int)((unsigned int)f2h(sl)  | ((unsigned int)sh << 16));  // 12,13
    w1[3] = 0;
    *(int4v*)g0 = z;
    *(int4v*)g1 = w1;
    int r0 = jt - 3;
    unsigned short hb0 = f2h(b0), hb1 = f2h(b1), hb2 = f2h(b2), hb3 = f2h(b3);
#pragma unroll
    for (int j = 0; j < 4; j++) {
        int s = r0 + j;
        unsigned short hv = (j == 0) ? hb0 : (j == 1) ? hb1 : (j == 2) ? hb2 : hb3;
        if ((unsigned)s <= 10u) {
            short* sp = (s < 8) ? (short*)g0 : (short*)g1;
            sp[s & 7] = (short)hv;
        }
    }
}

// LDS (dwords): A-slices 4 waves x 64 rows x 16 dw (group-rotation swizzle:
// row r, logical group g at physical group ((r>>1)+g)&3), then ybuf 256x17.
#define YBOFF 4096

// ---------------------------------------------------------------------------
// Stage 2: KAN via fp16 MFMA. Block = 256 thr = 4 waves; wave owns 64 px.
// B-frags from precomputed global tensor (L2-resident). No __syncthreads.
// ---------------------------------------------------------------------------
__global__ __launch_bounds__(256) void kan_mfma(const float* __restrict__ x,
                                                const unsigned int* __restrict__ bt,
                                                float* __restrict__ out) {
    __shared__ __align__(16) int lds[YBOFF + 256 * 17];
    const int tid  = threadIdx.x;
    const int lane = tid & 63, wave = tid >> 6;
    const int quad = lane >> 4, nn = lane & 15;
    const int b = blockIdx.x / 196;
    const int px0 = (blockIdx.x - b * 196) * 256;
    const unsigned int* btb = bt + b * 4608;
    float* ybf = (float*)&lds[YBOFF];

    // write-side rotated group pointers for this thread's row (= lane)
    int* slice = &lds[wave * 1024];
    int* gp[4];
#pragma unroll
    for (int g = 0; g < 4; g++)
        gp[g] = slice + lane * 16 + ((((lane >> 1) + g) & 3) * 4);

    // read-side rotation (mt-independent)
    const int rot = (((nn >> 1) + quad) & 3) * 4;
    const int aob = wave * 1024 + nn * 16 + rot;

    const float* xg = x + (size_t)b * 3 * HW + px0 + tid;
    float xv0 = xg[0], xv1 = xg[HW], xv2 = xg[2 * HW];

    f32x4 acc[4];

    auto kstep = [&](int ks) {
        union { half8 h; int4v v; } bf;
        bf.v = *(const int4v*)(btb + ks * 256 + lane * 4);
        asm volatile("s_waitcnt lgkmcnt(0)" ::: "memory");
#pragma unroll
        for (int mt = 0; mt < 4; mt++) {
            union { half8 h; int4v v; } af;
            af.v = *(int4v*)&lds[aob + mt * 256];
            acc[mt] = __builtin_amdgcn_mfma_f32_16x16x32_f16(af.h, bf.h, acc[mt], 0, 0, 0);
        }
        asm volatile("" ::: "memory");
    };

    // ================= Layer 1 (K=48 -> 2 ksteps; ch3's B is zero) =========
#pragma unroll
    for (int mt = 0; mt < 4; mt++) acc[mt] = (f32x4){0.f, 0.f, 0.f, 0.f};
    scatter_row(gp[0], gp[1], xv0);
    scatter_row(gp[2], gp[3], xv1);
    kstep(0);
    scatter_row(gp[0], gp[1], xv2);      // groups 2,3 stale (ch1) but B==0 there
    kstep(1);
#pragma unroll
    for (int mt = 0; mt < 4; mt++)
#pragma unroll
        for (int r = 0; r < 4; r++)
            ybf[(wave * 64 + mt * 16 + quad * 4 + r) * 17 + nn] = acc[mt][r];
    asm volatile("s_waitcnt lgkmcnt(0)" ::: "memory");

    // ================= Layer 2 (K=256 -> 8 ksteps) =========================
#pragma unroll
    for (int mt = 0; mt < 4; mt++) acc[mt] = (f32x4){0.f, 0.f, 0.f, 0.f};
#pragma unroll 1
    for (int s = 0; s < 8; s++) {
        float y0 = ybf[tid * 17 + 2 * s];
        float y1 = ybf[tid * 17 + 2 * s + 1];
        scatter_row(gp[0], gp[1], y0);
        scatter_row(gp[2], gp[3], y1);
        kstep(2 + s);
    }
#pragma unroll
    for (int mt = 0; mt < 4; mt++)
#pragma unroll
        for (int r = 0; r < 4; r++)
            ybf[(wave * 64 + mt * 16 + quad * 4 + r) * 17 + nn] = acc[mt][r];
    asm volatile("s_waitcnt lgkmcnt(0)" ::: "memory");

    // ================= Layer 3 (K=256 -> 8 ksteps, N=3 used) ===============
#pragma unroll
    for (int mt = 0; mt < 4; mt++) acc[mt] = (f32x4){0.f, 0.f, 0.f, 0.f};
#pragma unroll 1
    for (int s = 0; s < 8; s++) {
        float y0 = ybf[tid * 17 + 2 * s];
        float y1 = ybf[tid * 17 + 2 * s + 1];
        scatter_row(gp[0], gp[1], y0);
        scatter_row(gp[2], gp[3], y1);
        kstep(10 + s);
    }

    // transpose D through ybuf for coalesced stores
    if (nn < 3) {
#pragma unroll
        for (int mt = 0; mt < 4; mt++)
#pragma unroll
            for (int r = 0; r < 4; r++)
                ybf[(wave * 64 + mt * 16 + quad * 4 + r) * 17 + nn] = acc[mt][r];
    }
    asm volatile("s_waitcnt lgkmcnt(0)" ::: "memory");
    float c0 = ybf[tid * 17 + 0];
    float c1 = ybf[tid * 17 + 1];
    float c2 = ybf[tid * 17 + 2];
    float* ob = out + (size_t)b * 3 * HW + px0 + tid;
    ob[0]      = c0;
    ob[HW]     = c1;
    ob[2 * HW] = c2;
}

// ---------------------------------------------------------------------------
extern "C" void kernel_launch(void* const* d_in, const int* in_sizes, int n_in,
                              void* d_out, int out_size, void* d_ws, size_t ws_size,
                              hipStream_t stream) {
    const float* x     = (const float*)d_in[0];   // (8,3,224,224)
    const float* feats = (const float*)d_in[1];   // (8,1000)
    const float* fcw   = (const float*)d_in[2];   // (4576,1000)
    const float* fcb   = (const float*)d_in[3];   // (4576,)
    float* outp = (float*)d_out;
    float* wbuf = (float*)d_ws;                               // 36608 floats
    unsigned int* btens = (unsigned int*)d_ws + 36608;        // 36864 dwords

    hipLaunchKernelGGL(gemm_w, dim3(286), dim3(64), 0, stream,
                       feats, fcw, fcb, wbuf);
    hipLaunchKernelGGL(pack_b, dim3(144), dim3(256), 0, stream,
                       wbuf, btens);
    hipLaunchKernelGGL(kan_mfma, dim3(8 * 196), dim3(256), 0, stream,
                       x, btens, outp);
}

// Round 7
// 116.295 us; speedup vs baseline: 1.6282x; 1.1145x over previous
//
#include <hip/hip_runtime.h>

#define HW   50176      // 224*224
#define NPAR 4576       // KAN_PARAMS_NUM

typedef _Float16 half8 __attribute__((ext_vector_type(8)));
typedef __attribute__((ext_vector_type(4))) float f32x4;
typedef __attribute__((ext_vector_type(4))) int int4v;

__device__ __forceinline__ unsigned short f2h(float f) {
    union { _Float16 h; unsigned short u; } c; c.h = (_Float16)f; return c.u;
}
__device__ __forceinline__ float h2f(unsigned short u) {
    union { _Float16 h; unsigned short u; } c; c.u = u; return (float)c.h;
}

// ---------------------------------------------------------------------------
// Stage 1: w[m][n] = features[m][:] . fc_w[n][:] + fc_b[n]  via fp16 MFMA.
// Split-K: 256-thr block = 4 waves; wave w covers ksteps w*8..w*8+7, then
// cross-wave LDS reduction. 286 blocks (16 n per block).
// features split hi+lo fp16 so only fcw's single fp16 rounding survives.
// ---------------------------------------------------------------------------
__global__ __launch_bounds__(256) void gemm_w(const float* __restrict__ feats,
                                              const float* __restrict__ fcw,
                                              const float* __restrict__ fcb,
                                              float* __restrict__ wout) {
    __shared__ float red[4][64][4];
    int tid = threadIdx.x, lane = tid & 63, wave = tid >> 6;
    int nn = lane & 15, quad = lane >> 4;
    int n = blockIdx.x * 16 + nn;
    const float* brow = fcw + (size_t)n * 1000;
    const float* arow = feats + nn * 1000;          // deref'd only if nn<8

    f32x4 acc = {0.f, 0.f, 0.f, 0.f};
#pragma unroll 4
    for (int s8 = 0; s8 < 8; s8++) {
        int kb = (wave * 8 + s8) * 32 + quad * 8;
        float4 a0 = {0,0,0,0}, a1 = {0,0,0,0}, b0 = {0,0,0,0}, b1 = {0,0,0,0};
        if (kb < 1000) {                            // 1000 % 8 == 0
            b0 = *(const float4*)(brow + kb);
            b1 = *(const float4*)(brow + kb + 4);
            if (nn < 8) {
                a0 = *(const float4*)(arow + kb);
                a1 = *(const float4*)(arow + kb + 4);
            }
        }
        float af[8] = {a0.x, a0.y, a0.z, a0.w, a1.x, a1.y, a1.z, a1.w};
        float bf[8] = {b0.x, b0.y, b0.z, b0.w, b1.x, b1.y, b1.z, b1.w};
        half8 ah, al, bh;
#pragma unroll
        for (int j = 0; j < 8; j++) {
            ah[j] = (_Float16)af[j];
            al[j] = (_Float16)(af[j] - (float)ah[j]);
            bh[j] = (_Float16)bf[j];
        }
        acc = __builtin_amdgcn_mfma_f32_16x16x32_f16(ah, bh, acc, 0, 0, 0);
        acc = __builtin_amdgcn_mfma_f32_16x16x32_f16(al, bh, acc, 0, 0, 0);
    }
#pragma unroll
    for (int r = 0; r < 4; r++) red[wave][lane][r] = acc[r];
    __syncthreads();
    if (wave == 0 && quad < 2) {                     // rows m = quad*4+r in [0,8)
        float bias = fcb[n];
#pragma unroll
        for (int r = 0; r < 4; r++) {
            float v = red[0][lane][r] + red[1][lane][r]
                    + red[2][lane][r] + red[3][lane][r];
            wout[(size_t)(quad * 4 + r) * NPAR + n] = v + bias;
        }
    }
}

// ---------------------------------------------------------------------------
// Stage 1.5: build frag-ready fp16 B tensor in ws.
// bt[b*4608 + ks*256 + ln*4 + dq], ks: 0-1 L1, 2-9 L2, 10-17 L3.
// Lane ln (q=ln>>4, n=ln&15) dword dq holds halves rk=(q&1)*8+dq*2+{0,1} of
// channel i=2s+(q>>1): rk<11 -> coef*uw, 11/12 -> rw, 13 -> rw_lo, 14/15 -> 0.
// ---------------------------------------------------------------------------
__global__ __launch_bounds__(256) void pack_b(const float* __restrict__ w,
                                              unsigned int* __restrict__ bt) {
    int idx = blockIdx.x * 256 + threadIdx.x;       // < 36864
    if (idx >= 8 * 4608) return;
    int b = idx / 4608, r = idx - b * 4608;
    int ks = r >> 8, ln = (r >> 2) & 63, dq = r & 3;
    int q = ln >> 4, n = ln & 15;
    int lay, s;
    if (ks < 2)       { lay = 0; s = ks; }
    else if (ks < 10) { lay = 1; s = ks - 2; }
    else              { lay = 2; s = ks - 10; }
    int i = 2 * s + (q >> 1);
    const float* wb = w + b * NPAR;
    int cb, ub, rb2, nd, ni;
    if (lay == 0)      { cb = 0;    ub = 528;  rb2 = 576;  nd = 16; ni = 3;  }
    else if (lay == 1) { cb = 624;  ub = 3440; rb2 = 3696; nd = 16; ni = 16; }
    else               { cb = 3952; ub = 4480; rb2 = 4528; nd = 3;  ni = 16; }
    unsigned int pk = 0;
    if (i < ni && n < nd) {
        float uwv = wb[ub + i * nd + n];
        float rwv = wb[rb2 + i * nd + n];
        unsigned short rh = f2h(rwv);
        float rl = rwv - h2f(rh);
#pragma unroll
        for (int h = 0; h < 2; h++) {
            int rk = (q & 1) * 8 + dq * 2 + h;
            float v = 0.f;
            if (rk < 11)       v = wb[cb + (i * nd + n) * 11 + rk] * uwv;
            else if (rk < 13)  v = rwv;
            else if (rk == 13) v = rl;
            pk |= ((unsigned int)f2h(v)) << (16 * h);
        }
    }
    bt[idx] = pk;
}

// ---------------------------------------------------------------------------
// Scatter one channel-row (16 fp16 slots) into its two 4-dword LDS groups.
// g0: slots 0-7, g1: slots 8-15.
//   slots 0-10: cardinal cubic taps at jt-3..jt; out-of-range taps redirect
//   to slot 15 (B is zero there -> multiplied away). Branchless, no exec ops.
//   slot 11 = sil_hi, 12 = sil_lo, 13 = sil_hi, 14-15 = don't-care (B=0).
// ---------------------------------------------------------------------------
__device__ __forceinline__ void scatter_row(int* g0, int* g1, float y) {
    float t  = (y + 1.75f) * 4.0f;
    float ft = floorf(t);
    ft = fminf(fmaxf(ft, -8.0f), 24.0f);
    int jt  = (int)ft;
    float u = t - ft;
    float u2 = u * u, u3 = u2 * u, om = 1.0f - u;
    float b0 = (1.0f / 6.0f) * om * om * om;
    float b3 = (1.0f / 6.0f) * u3;
    float b1 = 0.5f * u3 - u2 + (2.0f / 3.0f);
    float b2 = 1.0f - b0 - b1 - b3;
    float sil = y / (1.0f + __expf(-y));
    unsigned short sh = f2h(sil);
    float sl = sil - h2f(sh);
    int4v z = {0, 0, 0, 0};
    int4v w1;
    w1[0] = 0;
    w1[1] = (int)((unsigned int)sh << 16);                             // 10(=0),11
    w1[2] = (int)((unsigned int)f2h(sl) | ((unsigned int)sh << 16));   // 12,13
    w1[3] = 0;
    *(int4v*)g0 = z;
    *(int4v*)g1 = w1;
    int r0 = jt - 3;
    unsigned short hb[4] = {f2h(b0), f2h(b1), f2h(b2), f2h(b3)};
#pragma unroll
    for (int j = 0; j < 4; j++) {
        int s = r0 + j;
        int slot = ((unsigned)s <= 10u) ? s : 15;   // OOR -> dead slot 15
        short* sp = (short*)((slot < 8) ? g0 : g1);
        sp[slot & 7] = (short)hb[j];
    }
}

// LDS (dwords): A-slices 4 waves x 64 rows x 16 dw (group-rotation swizzle:
// row r, logical group g at physical group ((r>>1)+g)&3), then ybuf 256x17.
#define YBOFF 4096

// ---------------------------------------------------------------------------
// Stage 2: KAN via fp16 MFMA. Block = 256 thr = 4 waves; wave owns 64 px.
// B-frags from precomputed global tensor (L2-resident). No __syncthreads.
// ---------------------------------------------------------------------------
__global__ __launch_bounds__(256) void kan_mfma(const float* __restrict__ x,
                                                const unsigned int* __restrict__ bt,
                                                float* __restrict__ out) {
    __shared__ __align__(16) int lds[YBOFF + 256 * 17];
    const int tid  = threadIdx.x;
    const int lane = tid & 63, wave = tid >> 6;
    const int quad = lane >> 4, nn = lane & 15;
    const int b = blockIdx.x / 196;
    const int px0 = (blockIdx.x - b * 196) * 256;
    const unsigned int* btb = bt + b * 4608;
    float* ybf = (float*)&lds[YBOFF];

    // write-side rotated group pointers for this thread's row (= lane)
    int* slice = &lds[wave * 1024];
    int* gp[4];
#pragma unroll
    for (int g = 0; g < 4; g++)
        gp[g] = slice + lane * 16 + ((((lane >> 1) + g) & 3) * 4);

    // read-side rotation (mt-independent)
    const int rot = (((nn >> 1) + quad) & 3) * 4;
    const int aob = wave * 1024 + nn * 16 + rot;

    const float* xg = x + (size_t)b * 3 * HW + px0 + tid;
    float xv0 = xg[0], xv1 = xg[HW], xv2 = xg[2 * HW];

    f32x4 acc[4];

    auto kstep = [&](int ks) {
        union { half8 h; int4v v; } bf;
        bf.v = *(const int4v*)(btb + ks * 256 + lane * 4);
        asm volatile("s_waitcnt lgkmcnt(0)" ::: "memory");
#pragma unroll
        for (int mt = 0; mt < 4; mt++) {
            union { half8 h; int4v v; } af;
            af.v = *(int4v*)&lds[aob + mt * 256];
            acc[mt] = __builtin_amdgcn_mfma_f32_16x16x32_f16(af.h, bf.h, acc[mt], 0, 0, 0);
        }
        asm volatile("" ::: "memory");
    };

    // ================= Layer 1 (K=48 -> 2 ksteps; ch3's B is zero) =========
#pragma unroll
    for (int mt = 0; mt < 4; mt++) acc[mt] = (f32x4){0.f, 0.f, 0.f, 0.f};
    scatter_row(gp[0], gp[1], xv0);
    scatter_row(gp[2], gp[3], xv1);
    kstep(0);
    scatter_row(gp[0], gp[1], xv2);      // groups 2,3 stale (ch1) but B==0 there
    kstep(1);
#pragma unroll
    for (int mt = 0; mt < 4; mt++)
#pragma unroll
        for (int r = 0; r < 4; r++)
            ybf[(wave * 64 + mt * 16 + quad * 4 + r) * 17 + nn] = acc[mt][r];
    asm volatile("s_waitcnt lgkmcnt(0)" ::: "memory");

    // ================= Layer 2 (K=256 -> 8 ksteps) =========================
#pragma unroll
    for (int mt = 0; mt < 4; mt++) acc[mt] = (f32x4){0.f, 0.f, 0.f, 0.f};
#pragma unroll 1
    for (int s = 0; s < 8; s++) {
        float y0 = ybf[tid * 17 + 2 * s];
        float y1 = ybf[tid * 17 + 2 * s + 1];
        scatter_row(gp[0], gp[1], y0);
        scatter_row(gp[2], gp[3], y1);
        kstep(2 + s);
    }
#pragma unroll
    for (int mt = 0; mt < 4; mt++)
#pragma unroll
        for (int r = 0; r < 4; r++)
            ybf[(wave * 64 + mt * 16 + quad * 4 + r) * 17 + nn] = acc[mt][r];
    asm volatile("s_waitcnt lgkmcnt(0)" ::: "memory");

    // ================= Layer 3 (K=256 -> 8 ksteps, N=3 used) ===============
#pragma unroll
    for (int mt = 0; mt < 4; mt++) acc[mt] = (f32x4){0.f, 0.f, 0.f, 0.f};
#pragma unroll 1
    for (int s = 0; s < 8; s++) {
        float y0 = ybf[tid * 17 + 2 * s];
        float y1 = ybf[tid * 17 + 2 * s + 1];
        scatter_row(gp[0], gp[1], y0);
        scatter_row(gp[2], gp[3], y1);
        kstep(10 + s);
    }

    // transpose D through ybuf for coalesced stores
    if (nn < 3) {
#pragma unroll
        for (int mt = 0; mt < 4; mt++)
#pragma unroll
            for (int r = 0; r < 4; r++)
                ybf[(wave * 64 + mt * 16 + quad * 4 + r) * 17 + nn] = acc[mt][r];
    }
    asm volatile("s_waitcnt lgkmcnt(0)" ::: "memory");
    float c0 = ybf[tid * 17 + 0];
    float c1 = ybf[tid * 17 + 1];
    float c2 = ybf[tid * 17 + 2];
    float* ob = out + (size_t)b * 3 * HW + px0 + tid;
    ob[0]      = c0;
    ob[HW]     = c1;
    ob[2 * HW] = c2;
}

// ---------------------------------------------------------------------------
extern "C" void kernel_launch(void* const* d_in, const int* in_sizes, int n_in,
                              void* d_out, int out_size, void* d_ws, size_t ws_size,
                              hipStream_t stream) {
    const float* x     = (const float*)d_in[0];   // (8,3,224,224)
    const float* feats = (const float*)d_in[1];   // (8,1000)
    const float* fcw   = (const float*)d_in[2];   // (4576,1000)
    const float* fcb   = (const float*)d_in[3];   // (4576,)
    float* outp = (float*)d_out;
    float* wbuf = (float*)d_ws;                               // 36608 floats
    unsigned int* btens = (unsigned int*)d_ws + 36608;        // 36864 dwords

    hipLaunchKernelGGL(gemm_w, dim3(286), dim3(256), 0, stream,
                       feats, fcw, fcb, wbuf);
    hipLaunchKernelGGL(pack_b, dim3(144), dim3(256), 0, stream,
                       wbuf, btens);
    hipLaunchKernelGGL(kan_mfma, dim3(8 * 196), dim3(256), 0, stream,
                       x, btens, outp);
}

// Round 8
// 114.441 us; speedup vs baseline: 1.6546x; 1.0162x over previous
//
#include <hip/hip_runtime.h>

#define HW   50176      // 224*224
#define NPAR 4576       // KAN_PARAMS_NUM

typedef _Float16 half8 __attribute__((ext_vector_type(8)));
typedef __attribute__((ext_vector_type(4))) float f32x4;
typedef __attribute__((ext_vector_type(4))) int int4v;

__device__ __forceinline__ unsigned short f2h(float f) {
    union { _Float16 h; unsigned short u; } c; c.h = (_Float16)f; return c.u;
}
__device__ __forceinline__ float h2f(unsigned short u) {
    union { _Float16 h; unsigned short u; } c; c.u = u; return (float)c.h;
}

// ---------------------------------------------------------------------------
// Stage 1: w[m][n] = features[m][:] . fc_w[n][:] + fc_b[n]  via fp16 MFMA.
// Split-K: 256-thr block = 4 waves; wave w covers ksteps w*8..w*8+7, then
// cross-wave LDS reduction. 286 blocks (16 n per block).
// ---------------------------------------------------------------------------
__global__ __launch_bounds__(256) void gemm_w(const float* __restrict__ feats,
                                              const float* __restrict__ fcw,
                                              const float* __restrict__ fcb,
                                              float* __restrict__ wout) {
    __shared__ float red[4][64][4];
    int tid = threadIdx.x, lane = tid & 63, wave = tid >> 6;
    int nn = lane & 15, quad = lane >> 4;
    int n = blockIdx.x * 16 + nn;
    const float* brow = fcw + (size_t)n * 1000;
    const float* arow = feats + nn * 1000;          // deref'd only if nn<8

    f32x4 acc = {0.f, 0.f, 0.f, 0.f};
#pragma unroll 4
    for (int s8 = 0; s8 < 8; s8++) {
        int kb = (wave * 8 + s8) * 32 + quad * 8;
        float4 a0 = {0,0,0,0}, a1 = {0,0,0,0}, b0 = {0,0,0,0}, b1 = {0,0,0,0};
        if (kb < 1000) {                            // 1000 % 8 == 0
            b0 = *(const float4*)(brow + kb);
            b1 = *(const float4*)(brow + kb + 4);
            if (nn < 8) {
                a0 = *(const float4*)(arow + kb);
                a1 = *(const float4*)(arow + kb + 4);
            }
        }
        float af[8] = {a0.x, a0.y, a0.z, a0.w, a1.x, a1.y, a1.z, a1.w};
        float bf[8] = {b0.x, b0.y, b0.z, b0.w, b1.x, b1.y, b1.z, b1.w};
        half8 ah, al, bh;
#pragma unroll
        for (int j = 0; j < 8; j++) {
            ah[j] = (_Float16)af[j];
            al[j] = (_Float16)(af[j] - (float)ah[j]);
            bh[j] = (_Float16)bf[j];
        }
        acc = __builtin_amdgcn_mfma_f32_16x16x32_f16(ah, bh, acc, 0, 0, 0);
        acc = __builtin_amdgcn_mfma_f32_16x16x32_f16(al, bh, acc, 0, 0, 0);
    }
#pragma unroll
    for (int r = 0; r < 4; r++) red[wave][lane][r] = acc[r];
    __syncthreads();
    if (wave == 0 && quad < 2) {                     // rows m = quad*4+r in [0,8)
        float bias = fcb[n];
#pragma unroll
        for (int r = 0; r < 4; r++) {
            float v = red[0][lane][r] + red[1][lane][r]
                    + red[2][lane][r] + red[3][lane][r];
            wout[(size_t)(quad * 4 + r) * NPAR + n] = v + bias;
        }
    }
}

// ---------------------------------------------------------------------------
// Stage 1.5: build frag-ready fp16 B tensor in ws.
// bt[b*4608 + ks*256 + ln*4 + dq], ks: 0-1 L1, 2-9 L2, 10-17 L3.
// ---------------------------------------------------------------------------
__global__ __launch_bounds__(256) void pack_b(const float* __restrict__ w,
                                              unsigned int* __restrict__ bt) {
    int idx = blockIdx.x * 256 + threadIdx.x;       // < 36864
    if (idx >= 8 * 4608) return;
    int b = idx / 4608, r = idx - b * 4608;
    int ks = r >> 8, ln = (r >> 2) & 63, dq = r & 3;
    int q = ln >> 4, n = ln & 15;
    int lay, s;
    if (ks < 2)       { lay = 0; s = ks; }
    else if (ks < 10) { lay = 1; s = ks - 2; }
    else              { lay = 2; s = ks - 10; }
    int i = 2 * s + (q >> 1);
    const float* wb = w + b * NPAR;
    int cb, ub, rb2, nd, ni;
    if (lay == 0)      { cb = 0;    ub = 528;  rb2 = 576;  nd = 16; ni = 3;  }
    else if (lay == 1) { cb = 624;  ub = 3440; rb2 = 3696; nd = 16; ni = 16; }
    else               { cb = 3952; ub = 4480; rb2 = 4528; nd = 3;  ni = 16; }
    unsigned int pk = 0;
    if (i < ni && n < nd) {
        float uwv = wb[ub + i * nd + n];
        float rwv = wb[rb2 + i * nd + n];
        unsigned short rh = f2h(rwv);
        float rl = rwv - h2f(rh);
#pragma unroll
        for (int h = 0; h < 2; h++) {
            int rk = (q & 1) * 8 + dq * 2 + h;
            float v = 0.f;
            if (rk < 11)       v = wb[cb + (i * nd + n) * 11 + rk] * uwv;
            else if (rk < 13)  v = rwv;
            else if (rk == 13) v = rl;
            pk |= ((unsigned int)f2h(v)) << (16 * h);
        }
    }
    bt[idx] = pk;
}

// ---------------------------------------------------------------------------
// Scatter one channel-row (16 fp16 slots) into its two 4-dword LDS groups.
//   slots 0-10: cardinal cubic taps at jt-3..jt; out-of-range taps redirect
//   to dead slot 15 (B zero there). Branchless.
//   slot 11 = sil_hi, 12 = sil_lo, 13 = sil_hi, 14-15 = don't-care (B=0).
// ---------------------------------------------------------------------------
__device__ __forceinline__ void scatter_row(int* g0, int* g1, float y) {
    float t  = (y + 1.75f) * 4.0f;
    float ft = floorf(t);
    ft = fminf(fmaxf(ft, -8.0f), 24.0f);
    int jt  = (int)ft;
    float u = t - ft;
    float u2 = u * u, u3 = u2 * u, om = 1.0f - u;
    float b0 = (1.0f / 6.0f) * om * om * om;
    float b3 = (1.0f / 6.0f) * u3;
    float b1 = 0.5f * u3 - u2 + (2.0f / 3.0f);
    float b2 = 1.0f - b0 - b1 - b3;
    float sil = y / (1.0f + __expf(-y));
    unsigned short sh = f2h(sil);
    float sl = sil - h2f(sh);
    int4v z = {0, 0, 0, 0};
    int4v w1;
    w1[0] = 0;
    w1[1] = (int)((unsigned int)sh << 16);                             // 10(=0),11
    w1[2] = (int)((unsigned int)f2h(sl) | ((unsigned int)sh << 16));   // 12,13
    w1[3] = 0;
    *(int4v*)g0 = z;
    *(int4v*)g1 = w1;
    int r0 = jt - 3;
    unsigned short hb[4] = {f2h(b0), f2h(b1), f2h(b2), f2h(b3)};
#pragma unroll
    for (int j = 0; j < 4; j++) {
        int s = r0 + j;
        int slot = ((unsigned)s <= 10u) ? s : 15;   // OOR -> dead slot 15
        short* sp = (short*)((slot < 8) ? g0 : g1);
        sp[slot & 7] = (short)hb[j];
    }
}

// LDS (dwords): A-slice 64 rows x 16 dw (group-rotation swizzle: row r,
// logical group g at physical group ((r>>1)+g)&3), then ybuf 64 x 17.
#define YBOFF 1024

// ---------------------------------------------------------------------------
// Stage 2: KAN via fp16 MFMA. Block = 1 wave = 64 px. ~8.4 KB LDS ->
// ~19 blocks/CU (vs 16 waves at 4x256-thr) for better latency hiding.
// No __syncthreads anywhere; wave-internal lgkmcnt fences only.
// ---------------------------------------------------------------------------
__global__ __launch_bounds__(64) void kan_mfma(const float* __restrict__ x,
                                               const unsigned int* __restrict__ bt,
                                               float* __restrict__ out) {
    __shared__ __align__(16) int lds[YBOFF + 64 * 17];
    const int lane = threadIdx.x;
    const int quad = lane >> 4, nn = lane & 15;
    const int b = blockIdx.x / 784;
    const int px0 = (blockIdx.x - b * 784) * 64;
    const unsigned int* btb = bt + b * 4608;
    float* ybf = (float*)&lds[YBOFF];

    // write-side rotated group pointers for this thread's row (= lane)
    int* gp[4];
#pragma unroll
    for (int g = 0; g < 4; g++)
        gp[g] = &lds[lane * 16 + ((((lane >> 1) + g) & 3) * 4)];

    // read-side rotation (mt-independent)
    const int aob = nn * 16 + (((nn >> 1) + quad) & 3) * 4;

    const float* xg = x + (size_t)b * 3 * HW + px0 + lane;
    float xv0 = xg[0], xv1 = xg[HW], xv2 = xg[2 * HW];

    f32x4 acc[4];

    auto kstep = [&](int ks) {
        union { half8 h; int4v v; } bf;
        bf.v = *(const int4v*)(btb + ks * 256 + lane * 4);
        asm volatile("s_waitcnt lgkmcnt(0)" ::: "memory");
#pragma unroll
        for (int mt = 0; mt < 4; mt++) {
            union { half8 h; int4v v; } af;
            af.v = *(int4v*)&lds[aob + mt * 256];
            acc[mt] = __builtin_amdgcn_mfma_f32_16x16x32_f16(af.h, bf.h, acc[mt], 0, 0, 0);
        }
    };

    // ================= Layer 1 (K=48 -> 2 ksteps; ch3's B is zero) =========
#pragma unroll
    for (int mt = 0; mt < 4; mt++) acc[mt] = (f32x4){0.f, 0.f, 0.f, 0.f};
    scatter_row(gp[0], gp[1], xv0);
    scatter_row(gp[2], gp[3], xv1);
    kstep(0);
    asm volatile("" ::: "memory");       // keep scatter below prior reads
    scatter_row(gp[0], gp[1], xv2);      // groups 2,3 stale (ch1) but B==0 there
    kstep(1);
#pragma unroll
    for (int mt = 0; mt < 4; mt++)
#pragma unroll
        for (int r = 0; r < 4; r++)
            ybf[(mt * 16 + quad * 4 + r) * 17 + nn] = acc[mt][r];
    asm volatile("s_waitcnt lgkmcnt(0)" ::: "memory");

    // ================= Layer 2 (K=256 -> 8 ksteps) =========================
#pragma unroll
    for (int mt = 0; mt < 4; mt++) acc[mt] = (f32x4){0.f, 0.f, 0.f, 0.f};
#pragma unroll 1
    for (int s = 0; s < 8; s++) {
        float y0 = ybf[lane * 17 + 2 * s];
        float y1 = ybf[lane * 17 + 2 * s + 1];
        asm volatile("" ::: "memory");
        scatter_row(gp[0], gp[1], y0);
        scatter_row(gp[2], gp[3], y1);
        kstep(2 + s);
    }
#pragma unroll
    for (int mt = 0; mt < 4; mt++)
#pragma unroll
        for (int r = 0; r < 4; r++)
            ybf[(mt * 16 + quad * 4 + r) * 17 + nn] = acc[mt][r];
    asm volatile("s_waitcnt lgkmcnt(0)" ::: "memory");

    // ================= Layer 3 (K=256 -> 8 ksteps, N=3 used) ===============
#pragma unroll
    for (int mt = 0; mt < 4; mt++) acc[mt] = (f32x4){0.f, 0.f, 0.f, 0.f};
#pragma unroll 1
    for (int s = 0; s < 8; s++) {
        float y0 = ybf[lane * 17 + 2 * s];
        float y1 = ybf[lane * 17 + 2 * s + 1];
        asm volatile("" ::: "memory");
        scatter_row(gp[0], gp[1], y0);
        scatter_row(gp[2], gp[3], y1);
        kstep(10 + s);
    }

    // transpose D through ybuf for coalesced stores
    if (nn < 3) {
#pragma unroll
        for (int mt = 0; mt < 4; mt++)
#pragma unroll
            for (int r = 0; r < 4; r++)
                ybf[(mt * 16 + quad * 4 + r) * 17 + nn] = acc[mt][r];
    }
    asm volatile("s_waitcnt lgkmcnt(0)" ::: "memory");
    float c0 = ybf[lane * 17 + 0];
    float c1 = ybf[lane * 17 + 1];
    float c2 = ybf[lane * 17 + 2];
    float* ob = out + (size_t)b * 3 * HW + px0 + lane;
    ob[0]      = c0;
    ob[HW]     = c1;
    ob[2 * HW] = c2;
}

// ---------------------------------------------------------------------------
extern "C" void kernel_launch(void* const* d_in, const int* in_sizes, int n_in,
                              void* d_out, int out_size, void* d_ws, size_t ws_size,
                              hipStream_t stream) {
    const float* x     = (const float*)d_in[0];   // (8,3,224,224)
    const float* feats = (const float*)d_in[1];   // (8,1000)
    const float* fcw   = (const float*)d_in[2];   // (4576,1000)
    const float* fcb   = (const float*)d_in[3];   // (4576,)
    float* outp = (float*)d_out;
    float* wbuf = (float*)d_ws;                               // 36608 floats
    unsigned int* btens = (unsigned int*)d_ws + 36608;        // 36864 dwords

    hipLaunchKernelGGL(gemm_w, dim3(286), dim3(256), 0, stream,
                       feats, fcw, fcb, wbuf);
    hipLaunchKernelGGL(pack_b, dim3(144), dim3(256), 0, stream,
                       wbuf, btens);
    hipLaunchKernelGGL(kan_mfma, dim3(8 * 784), dim3(64), 0, stream,
                       x, btens, outp);
}

// Round 11
// 113.962 us; speedup vs baseline: 1.6615x; 1.0042x over previous
//
#include <hip/hip_runtime.h>

#define HW   50176      // 224*224
#define NPAR 4576       // KAN_PARAMS_NUM

typedef _Float16 half8 __attribute__((ext_vector_type(8)));
typedef __fp16 fp16x2 __attribute__((ext_vector_type(2)));
typedef __attribute__((ext_vector_type(4))) float f32x4;
typedef __attribute__((ext_vector_type(4))) int int4v;

__device__ __forceinline__ unsigned short f2h(float f) {
    union { _Float16 h; unsigned short u; } c; c.h = (_Float16)f; return c.u;
}
__device__ __forceinline__ float h2f(unsigned short u) {
    union { _Float16 h; unsigned short u; } c; c.u = u; return (float)c.h;
}

// ---------------------------------------------------------------------------
// Stage 1: w[m][n] = features[m][:] . fc_w[n][:] + fc_b[n]  via fp16 MFMA.
// Split-K across 4 waves + LDS reduction. 286 blocks (16 n each).
// ---------------------------------------------------------------------------
__global__ __launch_bounds__(256) void gemm_w(const float* __restrict__ feats,
                                              const float* __restrict__ fcw,
                                              const float* __restrict__ fcb,
                                              float* __restrict__ wout) {
    __shared__ float red[4][64][4];
    int tid = threadIdx.x, lane = tid & 63, wave = tid >> 6;
    int nn = lane & 15, quad = lane >> 4;
    int n = blockIdx.x * 16 + nn;
    const float* brow = fcw + (size_t)n * 1000;
    const float* arow = feats + nn * 1000;          // deref'd only if nn<8

    f32x4 acc = {0.f, 0.f, 0.f, 0.f};
#pragma unroll 4
    for (int s8 = 0; s8 < 8; s8++) {
        int kb = (wave * 8 + s8) * 32 + quad * 8;
        float4 a0 = {0,0,0,0}, a1 = {0,0,0,0}, b0 = {0,0,0,0}, b1 = {0,0,0,0};
        if (kb < 1000) {                            // 1000 % 8 == 0
            b0 = *(const float4*)(brow + kb);
            b1 = *(const float4*)(brow + kb + 4);
            if (nn < 8) {
                a0 = *(const float4*)(arow + kb);
                a1 = *(const float4*)(arow + kb + 4);
            }
        }
        float af[8] = {a0.x, a0.y, a0.z, a0.w, a1.x, a1.y, a1.z, a1.w};
        float bf[8] = {b0.x, b0.y, b0.z, b0.w, b1.x, b1.y, b1.z, b1.w};
        half8 ah, al, bh;
#pragma unroll
        for (int j = 0; j < 8; j++) {
            ah[j] = (_Float16)af[j];
            al[j] = (_Float16)(af[j] - (float)ah[j]);
            bh[j] = (_Float16)bf[j];
        }
        acc = __builtin_amdgcn_mfma_f32_16x16x32_f16(ah, bh, acc, 0, 0, 0);
        acc = __builtin_amdgcn_mfma_f32_16x16x32_f16(al, bh, acc, 0, 0, 0);
    }
#pragma unroll
    for (int r = 0; r < 4; r++) red[wave][lane][r] = acc[r];
    __syncthreads();
    if (wave == 0 && quad < 2) {                     // rows m = quad*4+r in [0,8)
        float bias = fcb[n];
#pragma unroll
        for (int r = 0; r < 4; r++) {
            float v = red[0][lane][r] + red[1][lane][r]
                    + red[2][lane][r] + red[3][lane][r];
            wout[(size_t)(quad * 4 + r) * NPAR + n] = v + bias;
        }
    }
}

// ---------------------------------------------------------------------------
// Stage 1.5: build frag-ready fp16 B tensor in ws.
// bt[b*4608 + ks*256 + ln*4 + dq], ks: 0-1 L1, 2-9 L2, 10-17 L3.
// Slots rk<11 -> coef*uw, 11/12 -> rw, 13 -> rw_lo, 14/15 -> 0.
// ---------------------------------------------------------------------------
__global__ __launch_bounds__(256) void pack_b(const float* __restrict__ w,
                                              unsigned int* __restrict__ bt) {
    int idx = blockIdx.x * 256 + threadIdx.x;       // < 36864
    if (idx >= 8 * 4608) return;
    int b = idx / 4608, r = idx - b * 4608;
    int ks = r >> 8, ln = (r >> 2) & 63, dq = r & 3;
    int q = ln >> 4, n = ln & 15;
    int lay, s;
    if (ks < 2)       { lay = 0; s = ks; }
    else if (ks < 10) { lay = 1; s = ks - 2; }
    else              { lay = 2; s = ks - 10; }
    int i = 2 * s + (q >> 1);
    const float* wb = w + b * NPAR;
    int cb, ub, rb2, nd, ni;
    if (lay == 0)      { cb = 0;    ub = 528;  rb2 = 576;  nd = 16; ni = 3;  }
    else if (lay == 1) { cb = 624;  ub = 3440; rb2 = 3696; nd = 16; ni = 16; }
    else               { cb = 3952; ub = 4480; rb2 = 4528; nd = 3;  ni = 16; }
    unsigned int pk = 0;
    if (i < ni && n < nd) {
        float uwv = wb[ub + i * nd + n];
        float rwv = wb[rb2 + i * nd + n];
        unsigned short rh = f2h(rwv);
        float rl = rwv - h2f(rh);
#pragma unroll
        for (int h = 0; h < 2; h++) {
            int rk = (q & 1) * 8 + dq * 2 + h;
            float v = 0.f;
            if (rk < 11)       v = wb[cb + (i * nd + n) * 11 + rk] * uwv;
            else if (rk < 13)  v = rwv;
            else if (rk == 13) v = rl;
            pk |= ((unsigned int)f2h(v)) << (16 * h);
        }
    }
    bt[idx] = pk;
}

// ---------------------------------------------------------------------------
// Scatter one channel-row (16 fp16 slots = 8 dwords, 16B-aligned base).
// Store order (R8-proven): full image via two b128 int stores (zeros +
// statics), THEN taps as shorts; dead taps go ONLY to slot 15 (B=0 there),
// so statics at slots 11-13 are never clobbered.
//   slots 0-10: cubic taps at jt-3..jt; slot 11 = sil_hi, 12 = sil_lo,
//   13 = sil_hi(rtz), 14/15 = 0.
// ft clamped to [-8,24]; u clamped to +-8 keeps dead-tap values finite.
// ---------------------------------------------------------------------------
__device__ __forceinline__ void scatter_row(int* rowp, float y) {
    float t  = (y + 1.75f) * 4.0f;
    float ft = floorf(t);
    ft = fminf(fmaxf(ft, -8.0f), 24.0f);
    float u = t - ft;
    u = fminf(fmaxf(u, -8.0f), 8.0f);
    float u2 = u * u, u3 = u2 * u, om = 1.0f - u;
    float b0 = (1.0f / 6.0f) * om * om * om;
    float b3 = (1.0f / 6.0f) * u3;
    float b1 = 0.5f * u3 - u2 + (2.0f / 3.0f);
    float b2 = 1.0f - b0 - b1 - b3;
    float sil = y * __builtin_amdgcn_rcpf(1.0f + __expf(-y));

    unsigned short sh = f2h(sil);
    float sl = sil - h2f(sh);
    union { fp16x2 h; int i; } pk;
    pk.h = __builtin_amdgcn_cvt_pkrtz(sl, sil);  // lo=sil_lo, hi=sil_rtz

    int4v z = {0, 0, 0, 0};
    int4v w1;
    w1[0] = 0;                                   // slots 8,9
    w1[1] = (int)((unsigned int)sh << 16);       // slots 10(=0),11
    w1[2] = pk.i;                                // slots 12,13
    w1[3] = 0;                                   // slots 14,15
    *(int4v*)rowp = z;                           // slots 0-7
    *(int4v*)(rowp + 4) = w1;                    // slots 8-15

    int jt3 = (int)ft - 3;
    short* sp = (short*)rowp;
    unsigned short hb[4] = {f2h(b0), f2h(b1), f2h(b2), f2h(b3)};
#pragma unroll
    for (int j = 0; j < 4; j++) {
        int s = jt3 + j;
        int slot = ((unsigned)s <= 10u) ? s : 15;   // dead -> slot 15 (B=0)
        sp[slot] = (short)hb[j];
    }
}

// LDS (dwords): A 64 pixel-rows x 20 (content dw0-15: ch-even 0-7, ch-odd
// 8-15; stride 20 -> every row 16B-aligned AND bank-balanced for b128),
// then ybuf 64 x 18 (even stride -> aligned b64 reads).
#define ASTR  20
#define YSTR  18
#define YBOFF (64 * ASTR)     // 1280

// ---------------------------------------------------------------------------
// Stage 2: KAN via fp16 MFMA. Block = 1 wave = 64 px. 9.7 KB LDS.
// ---------------------------------------------------------------------------
__global__ __launch_bounds__(64) void kan_mfma(const float* __restrict__ x,
                                               const unsigned int* __restrict__ bt,
                                               float* __restrict__ out) {
    __shared__ __align__(16) int lds[YBOFF + 64 * YSTR];
    const int lane = threadIdx.x;
    const int quad = lane >> 4, nn = lane & 15;
    const int b = blockIdx.x / 784;
    const int px0 = (blockIdx.x - b * 784) * 64;
    const unsigned int* btb = bt + b * 4608;
    float* ybf = (float*)&lds[YBOFF];

    int* rowE = &lds[ASTR * lane];       // this pixel's even-channel row
    int* rowO = rowE + 8;                // odd-channel row
    const int aob = ASTR * nn + 4 * quad;

    const float* xg = x + (size_t)b * 3 * HW + px0 + lane;
    float xv0 = xg[0], xv1 = xg[HW], xv2 = xg[2 * HW];

    f32x4 acc[4];

    auto kstep = [&](int ks) {
        union { half8 h; int4v v; } bf;
        bf.v = *(const int4v*)(btb + ks * 256 + lane * 4);
        asm volatile("s_waitcnt lgkmcnt(0)" ::: "memory");
#pragma unroll
        for (int mt = 0; mt < 4; mt++) {
            union { half8 h; int4v v; } af;
            af.v = *(int4v*)&lds[aob + mt * (16 * ASTR)];
            acc[mt] = __builtin_amdgcn_mfma_f32_16x16x32_f16(af.h, bf.h, acc[mt], 0, 0, 0);
        }
    };

    // ================= Layer 1 (K=48 -> 2 ksteps; ch3's B is zero) =========
#pragma unroll
    for (int mt = 0; mt < 4; mt++) acc[mt] = (f32x4){0.f, 0.f, 0.f, 0.f};
    scatter_row(rowE, xv0);
    scatter_row(rowO, xv1);
    kstep(0);
    asm volatile("" ::: "memory");
    scatter_row(rowE, xv2);              // odd row stale (ch1) but B==0 there
    kstep(1);
#pragma unroll
    for (int mt = 0; mt < 4; mt++)
#pragma unroll
        for (int r = 0; r < 4; r++)
            ybf[(mt * 16 + quad * 4 + r) * YSTR + nn] = acc[mt][r];
    asm volatile("s_waitcnt lgkmcnt(0)" ::: "memory");

    // ================= Layer 2 (K=256 -> 8 ksteps) =========================
    {
        float yv[16];
#pragma unroll
        for (int j = 0; j < 8; j++) {
            float2 p = *(const float2*)&ybf[lane * YSTR + 2 * j];
            yv[2 * j] = p.x; yv[2 * j + 1] = p.y;
        }
#pragma unroll
        for (int mt = 0; mt < 4; mt++) acc[mt] = (f32x4){0.f, 0.f, 0.f, 0.f};
#pragma unroll 1
        for (int s = 0; s < 8; s++) {
            asm volatile("" ::: "memory");
            scatter_row(rowE, yv[2 * s]);
            scatter_row(rowO, yv[2 * s + 1]);
            kstep(2 + s);
        }
    }
#pragma unroll
    for (int mt = 0; mt < 4; mt++)
#pragma unroll
        for (int r = 0; r < 4; r++)
            ybf[(mt * 16 + quad * 4 + r) * YSTR + nn] = acc[mt][r];
    asm volatile("s_waitcnt lgkmcnt(0)" ::: "memory");

    // ================= Layer 3 (K=256 -> 8 ksteps, N=3 used) ===============
    {
        float yv[16];
#pragma unroll
        for (int j = 0; j < 8; j++) {
            float2 p = *(const float2*)&ybf[lane * YSTR + 2 * j];
            yv[2 * j] = p.x; yv[2 * j + 1] = p.y;
        }
#pragma unroll
        for (int mt = 0; mt < 4; mt++) acc[mt] = (f32x4){0.f, 0.f, 0.f, 0.f};
#pragma unroll 1
        for (int s = 0; s < 8; s++) {
            asm volatile("" ::: "memory");
            scatter_row(rowE, yv[2 * s]);
            scatter_row(rowO, yv[2 * s + 1]);
            kstep(10 + s);
        }
    }

    // transpose D through ybuf for coalesced stores
    if (nn < 3) {
#pragma unroll
        for (int mt = 0; mt < 4; mt++)
#pragma unroll
            for (int r = 0; r < 4; r++)
                ybf[(mt * 16 + quad * 4 + r) * YSTR + nn] = acc[mt][r];
    }
    asm volatile("s_waitcnt lgkmcnt(0)" ::: "memory");
    float c0 = ybf[lane * YSTR + 0];
    float c1 = ybf[lane * YSTR + 1];
    float c2 = ybf[lane * YSTR + 2];
    float* ob = out + (size_t)b * 3 * HW + px0 + lane;
    ob[0]      = c0;
    ob[HW]     = c1;
    ob[2 * HW] = c2;
}

// ---------------------------------------------------------------------------
extern "C" void kernel_launch(void* const* d_in, const int* in_sizes, int n_in,
                              void* d_out, int out_size, void* d_ws, size_t ws_size,
                              hipStream_t stream) {
    const float* x     = (const float*)d_in[0];   // (8,3,224,224)
    const float* feats = (const float*)d_in[1];   // (8,1000)
    const float* fcw   = (const float*)d_in[2];   // (4576,1000)
    const float* fcb   = (const float*)d_in[3];   // (4576,)
    float* outp = (float*)d_out;
    float* wbuf = (float*)d_ws;                               // 36608 floats
    unsigned int* btens = (unsigned int*)d_ws + 36608;        // 36864 dwords

    hipLaunchKernelGGL(gemm_w, dim3(286), dim3(256), 0, stream,
                       feats, fcw, fcb, wbuf);
    hipLaunchKernelGGL(pack_b, dim3(144), dim3(256), 0, stream,
                       wbuf, btens);
    hipLaunchKernelGGL(kan_mfma, dim3(8 * 784), dim3(64), 0, stream,
                       x, btens, outp);
}